// Round 3
// baseline (12961.848 us; speedup 1.0000x reference)
//
#include <hip/hip_runtime.h>

typedef unsigned short u16;
typedef _Float16 f16x8 __attribute__((ext_vector_type(8)));
typedef float f32x4 __attribute__((ext_vector_type(4)));

#define T_LEN 512
#define BATCH 32
#define DIN 42
#define HID 800
#define G4 3200
#define KCLS 20

__device__ __forceinline__ float h2f(u16 u){
    union { u16 u; _Float16 h; } v; v.u = u; return (float)v.h;
}
__device__ __forceinline__ u16 f2h(float f){
    union { _Float16 h; u16 u; } v; v.h = (_Float16)f; return v.u;
}
__device__ __forceinline__ float sigm(float x){ return 1.f / (1.f + expf(-x)); }

// ---------------- prep kernels ----------------
__global__ void k_cvt(const float* __restrict__ s, u16* __restrict__ d, int n){
    for (int i = blockIdx.x * blockDim.x + threadIdx.x; i < n; i += gridDim.x * blockDim.x)
        d[i] = f2h(s[i]);
}
// pack whh (3200,800) -> P[tile][64][800], row r: gate=r>>4, unit=tile*16+(r&15)
__global__ void k_pack_whh(const float* __restrict__ whh, u16* __restrict__ P){
    const int n = 50 * 64 * 800;
    for (int i = blockIdx.x * blockDim.x + threadIdx.x; i < n; i += gridDim.x * blockDim.x){
        int k = i % 800;
        int r = (i / 800) & 63;
        int tile = i / (800 * 64);
        int gt = r >> 4;
        int j = tile * 16 + (r & 15);
        P[i] = f2h(whh[(size_t)(gt * 800 + j) * 800 + k]);
    }
}
// x (B,T,D) fp32 -> xT (T*B, D) f16
__global__ void k_xT(const float* __restrict__ x, u16* __restrict__ xT){
    const int n = T_LEN * BATCH * DIN;
    for (int i = blockIdx.x * blockDim.x + threadIdx.x; i < n; i += gridDim.x * blockDim.x){
        int t = i / (BATCH * DIN);
        int rem = i % (BATCH * DIN);
        int b = rem / DIN, k = rem % DIN;
        xT[i] = f2h(x[((size_t)b * T_LEN + t) * DIN + k]);
    }
}
__global__ void k_zero16(u16* __restrict__ d, int n){
    for (int i = blockIdx.x * blockDim.x + threadIdx.x; i < n; i += gridDim.x * blockDim.x)
        d[i] = 0;
}

// ---------------- MFMA GEMM: C[M,N] = A[M,K] * B[N,K]^T + bias ----------------
// A f16 row-major; B f16 or fp32 row-major (b_is_f32); C f16 or fp32.
// 128x128 tile, 4 waves (2x2), 16x16x32 MFMA (f16).
__global__ __launch_bounds__(256) void mfma_gemm(
    const u16* __restrict__ Ag, int lda,
    const void* __restrict__ Bg_, int ldb,
    const float* __restrict__ bias,
    void* __restrict__ Cg, int ldc,
    int M, int N, int K, int out_f16, int b_is_f32)
{
    __shared__ u16 At[128 * 40];
    __shared__ u16 Bt[128 * 40];
    const u16*   Bu = (const u16*)Bg_;
    const float* Bf = (const float*)Bg_;
    const int tid = threadIdx.x;
    const int lane = tid & 63, w = tid >> 6;
    const int wr = w >> 1, wc = w & 1;
    const int lr = lane & 15, kb8 = (lane >> 4) * 8;
    const int m0 = blockIdx.y * 128, n0 = blockIdx.x * 128;
    const int sr = tid >> 1, skg = (tid & 1) << 4;
    f32x4 acc[4][4] = {};
    const int KT = (K + 31) >> 5;
    for (int kt = 0; kt < KT; ++kt){
        const int k0 = kt << 5;
        __syncthreads();
        { // stage A
            size_t base = (size_t)(m0 + sr) * lda + k0 + skg;
            if (((lda & 7) == 0) && (k0 + skg + 16 <= K)){
                const f16x8* p = (const f16x8*)(Ag + base);
                *(f16x8*)&At[sr * 40 + skg] = p[0];
                *(f16x8*)&At[sr * 40 + skg + 8] = p[1];
            } else {
                #pragma unroll
                for (int j = 0; j < 16; ++j){
                    int k = k0 + skg + j;
                    At[sr * 40 + skg + j] = (k < K) ? Ag[base + j] : (u16)0;
                }
            }
        }
        { // stage B
            int rn = n0 + sr;
            size_t base = (size_t)rn * ldb + k0 + skg;
            if ((!b_is_f32) && (rn < N) && ((ldb & 7) == 0) && (k0 + skg + 16 <= K)){
                const f16x8* p = (const f16x8*)(Bu + base);
                *(f16x8*)&Bt[sr * 40 + skg] = p[0];
                *(f16x8*)&Bt[sr * 40 + skg + 8] = p[1];
            } else {
                #pragma unroll
                for (int j = 0; j < 16; ++j){
                    int k = k0 + skg + j;
                    u16 v = 0;
                    if (rn < N && k < K)
                        v = b_is_f32 ? f2h(Bf[base + j]) : Bu[base + j];
                    Bt[sr * 40 + skg + j] = v;
                }
            }
        }
        __syncthreads();
        f16x8 af[4], bfr[4];
        #pragma unroll
        for (int mi = 0; mi < 4; ++mi)
            af[mi] = *(const f16x8*)&At[(wr * 64 + mi * 16 + lr) * 40 + kb8];
        #pragma unroll
        for (int ni = 0; ni < 4; ++ni)
            bfr[ni] = *(const f16x8*)&Bt[(wc * 64 + ni * 16 + lr) * 40 + kb8];
        #pragma unroll
        for (int mi = 0; mi < 4; ++mi)
            #pragma unroll
            for (int ni = 0; ni < 4; ++ni)
                acc[mi][ni] = __builtin_amdgcn_mfma_f32_16x16x32_f16(af[mi], bfr[ni], acc[mi][ni], 0, 0, 0);
    }
    #pragma unroll
    for (int mi = 0; mi < 4; ++mi){
        #pragma unroll
        for (int ni = 0; ni < 4; ++ni){
            int col = n0 + wc * 64 + ni * 16 + lr;
            if (col >= N) continue;
            float bs = bias ? bias[col] : 0.f;
            #pragma unroll
            for (int r = 0; r < 4; ++r){
                int row = m0 + wr * 64 + mi * 16 + ((lane >> 4) * 4 + r);
                float v = acc[mi][ni][r] + bs;
                if (out_f16) ((u16*)Cg)[(size_t)row * ldc + col] = f2h(v);
                else         ((float*)Cg)[(size_t)row * ldc + col] = v;
            }
        }
    }
}

// ---------------- LSTM step (both directions), gate-partitioned ----------------
// grid: 100 blocks (dir = blk/50, tile = blk%50), 256 threads = 4 waves.
__global__ __launch_bounds__(256) void lstm_step(
    const u16* __restrict__ xg_f, const u16* __restrict__ xg_b,
    const u16* __restrict__ whhP_f, const u16* __restrict__ whhP_b,
    const u16* __restrict__ hprev_f, const u16* __restrict__ hprev_b,
    u16* __restrict__ hout_f, u16* __restrict__ hout_b,
    float* __restrict__ c_f, float* __restrict__ c_b,
    int first)
{
    const int dir = blockIdx.x / 50;
    const int tile = blockIdx.x % 50;
    const u16* xg    = dir ? xg_b    : xg_f;
    const u16* whhP  = dir ? whhP_b  : whhP_f;
    const u16* hprev = dir ? hprev_b : hprev_f;
    u16* hout        = dir ? hout_b  : hout_f;
    float* cst       = dir ? c_b     : c_f;

    const int tid = threadIdx.x, lane = tid & 63, w = tid >> 6;
    const int mi = w >> 1, nh = w & 1;
    const int lr = lane & 15, kb8 = (lane >> 4) * 8;
    __shared__ float gLds[32][64];

    f32x4 acc0 = {}, acc1 = {};
    const int arow = mi * 16 + lr; // batch index
    const u16* aptr  = hprev + (size_t)arow * 1600 + kb8;
    const u16* bptr0 = whhP + ((size_t)(tile * 64 + nh * 32 + lr)) * 800 + kb8;
    const u16* bptr1 = whhP + ((size_t)(tile * 64 + nh * 32 + 16 + lr)) * 800 + kb8;
    #pragma unroll 5
    for (int kk = 0; kk < 25; ++kk){
        f16x8 a  = *(const f16x8*)(aptr  + kk * 32);
        f16x8 b0 = *(const f16x8*)(bptr0 + kk * 32);
        f16x8 b1 = *(const f16x8*)(bptr1 + kk * 32);
        acc0 = __builtin_amdgcn_mfma_f32_16x16x32_f16(a, b0, acc0, 0, 0, 0);
        acc1 = __builtin_amdgcn_mfma_f32_16x16x32_f16(a, b1, acc1, 0, 0, 0);
    }
    #pragma unroll
    for (int r = 0; r < 4; ++r){
        int b = mi * 16 + (lane >> 4) * 4 + r;
        gLds[b][nh * 32 + lr]      = acc0[r];
        gLds[b][nh * 32 + 16 + lr] = acc1[r];
    }
    __syncthreads();
    #pragma unroll
    for (int it = 0; it < 2; ++it){
        int item = tid + it * 256;      // 512 items: 32 b x 16 u
        int b = item >> 4, u = item & 15;
        int j = tile * 16 + u;
        float gi = gLds[b][u]        + h2f(xg[(size_t)b * G4 + j]);
        float gf = gLds[b][16 + u]   + h2f(xg[(size_t)b * G4 + 800 + j]);
        float gg = gLds[b][32 + u]   + h2f(xg[(size_t)b * G4 + 1600 + j]);
        float go = gLds[b][48 + u]   + h2f(xg[(size_t)b * G4 + 2400 + j]);
        float cp = first ? 0.f : cst[b * HID + j];
        float cn = sigm(gf) * cp + sigm(gi) * tanhf(gg);
        float hn = sigm(go) * tanhf(cn);
        cst[b * HID + j] = cn;
        hout[(size_t)b * 1600 + j] = f2h(hn);
    }
}

// ---------------- softmax over batch + angles ----------------
__global__ __launch_bounds__(64) void k_smax_ang(
    const float* __restrict__ logits, const float* __restrict__ alphabet,
    float* __restrict__ ang)
{
    int t = blockIdx.x;
    __shared__ float P[32][20];
    __shared__ float sA[20][3], cA[20][3];
    int tid = threadIdx.x;
    for (int idx = tid; idx < 32 * 20; idx += 64){
        int b = idx / 20, k = idx % 20;
        P[b][k] = logits[((size_t)t * 32 + b) * 20 + k];
    }
    for (int idx = tid; idx < 60; idx += 64){
        float al = alphabet[idx];
        sA[idx / 3][idx % 3] = sinf(al);
        cA[idx / 3][idx % 3] = cosf(al);
    }
    __syncthreads();
    if (tid < 20){
        float mx = -1e30f;
        for (int b = 0; b < 32; ++b) mx = fmaxf(mx, P[b][tid]);
        float s = 0.f;
        for (int b = 0; b < 32; ++b){ float e = expf(P[b][tid] - mx); P[b][tid] = e; s += e; }
        float inv = 1.f / s;
        for (int b = 0; b < 32; ++b) P[b][tid] *= inv;
    }
    __syncthreads();
    if (tid < 32){
        float sx = 0, sy = 0, sz = 0, cx = 0, cy = 0, cz = 0;
        for (int k = 0; k < 20; ++k){
            float p = P[tid][k];
            sx += p * sA[k][0]; sy += p * sA[k][1]; sz += p * sA[k][2];
            cx += p * cA[k][0]; cy += p * cA[k][1]; cz += p * cA[k][2];
        }
        size_t base = ((size_t)t * 32 + tid) * 3;
        ang[base + 0] = atan2f(sx, cx);
        ang[base + 1] = atan2f(sy, cy);
        ang[base + 2] = atan2f(sz, cz);
    }
}

// ---------------- sequential coordinate chain ----------------
__global__ __launch_bounds__(64) void k_coords(const float* __restrict__ ang, float* __restrict__ out){
    int b = threadIdx.x;
    if (b >= 32) return;
    float ax = 0.f, ay = 0.f, az = 1.f;
    float bx = 0.f, by = 1.f, bz = 1.f;
    float cx = 1.f, cy = 1.f, cz = 1.f;
    out[(0 * 32 + b) * 3 + 0] = ax; out[(0 * 32 + b) * 3 + 1] = ay; out[(0 * 32 + b) * 3 + 2] = az;
    out[(1 * 32 + b) * 3 + 0] = bx; out[(1 * 32 + b) * 3 + 1] = by; out[(1 * 32 + b) * 3 + 2] = bz;
    out[(2 * 32 + b) * 3 + 0] = cx; out[(2 * 32 + b) * 3 + 1] = cy; out[(2 * 32 + b) * 3 + 2] = cz;
    const float rr[3] = {145.801f, 152.326f, 132.868f};
    const float ba[3] = {2.124f, 1.941f, 2.028f};
    float ct[3], st[3];
    #pragma unroll
    for (int i = 0; i < 3; ++i){ ct[i] = cosf(ba[i]); st[i] = sinf(ba[i]); }
    for (int t = 0; t < T_LEN; ++t){
        #pragma unroll
        for (int i = 0; i < 3; ++i){
            float p = ang[((size_t)t * 32 + b) * 3 + i];
            float d2x = -rr[i] * ct[i];
            float d2y = rr[i] * cosf(p) * st[i];
            float d2z = rr[i] * sinf(p) * st[i];
            float bcx = cx - bx, bcy = cy - by, bcz = cz - bz;
            float inb = 1.f / sqrtf(bcx * bcx + bcy * bcy + bcz * bcz);
            bcx *= inb; bcy *= inb; bcz *= inb;
            float ux = bx - ax, uy = by - ay, uz = bz - az;
            float nx = uy * bcz - uz * bcy;
            float ny = uz * bcx - ux * bcz;
            float nz = ux * bcy - uy * bcx;
            float inn = 1.f / sqrtf(nx * nx + ny * ny + nz * nz);
            nx *= inn; ny *= inn; nz *= inn;
            float mx = ny * bcz - nz * bcy;  // cross(n, bc)
            float my = nz * bcx - nx * bcz;
            float mz = nx * bcy - ny * bcx;
            float dx = bcx * d2x + mx * d2y + nx * d2z + cx;
            float dy = bcy * d2x + my * d2y + ny * d2z + cy;
            float dz = bcz * d2x + mz * d2y + nz * d2z + cz;
            int row = 3 + t * 3 + i;
            out[((size_t)row * 32 + b) * 3 + 0] = dx;
            out[((size_t)row * 32 + b) * 3 + 1] = dy;
            out[((size_t)row * 32 + b) * 3 + 2] = dz;
            ax = bx; ay = by; az = bz;
            bx = cx; by = cy; bz = cz;
            cx = dx; cy = dy; cz = dz;
        }
    }
}

extern "C" void kernel_launch(void* const* d_in, const int* in_sizes, int n_in,
                              void* d_out, int out_size, void* d_ws, size_t ws_size,
                              hipStream_t stream)
{
    const float* x     = (const float*)d_in[0];
    const float* wih0f = (const float*)d_in[1];
    const float* whh0f = (const float*)d_in[2];
    const float* b0f   = (const float*)d_in[3];
    const float* wih0b = (const float*)d_in[4];
    const float* whh0b = (const float*)d_in[5];
    const float* b0b   = (const float*)d_in[6];
    const float* wih1f = (const float*)d_in[7];
    const float* whh1f = (const float*)d_in[8];
    const float* b1f   = (const float*)d_in[9];
    const float* wih1b = (const float*)d_in[10];
    const float* whh1b = (const float*)d_in[11];
    const float* b1b   = (const float*)d_in[12];
    const float* linw  = (const float*)d_in[13];
    const float* linb  = (const float*)d_in[14];
    const float* alpha = (const float*)d_in[15];
    (void)in_sizes; (void)n_in; (void)out_size;

    // ---- tier selection by ws_size ----
    auto pad = [](size_t b){ return (b + 255) & ~(size_t)255; };
    const size_t base_bytes =
        pad((size_t)T_LEN * BATCH * DIN * 2) +        // xT
        pad((size_t)T_LEN * BATCH * 1600 * 2) * 2 +   // h1, h2
        pad((size_t)G4 * DIN * 2) * 2 +               // w0fB, w0bB
        pad((size_t)G4 * HID * 2) * 4 +               // P0f..P1b
        pad((size_t)KCLS * 1600 * 2) +                // linwB
        pad((size_t)BATCH * 1600 * 2) +               // hzero
        pad((size_t)BATCH * HID * 4) * 4 +            // c states
        pad((size_t)T_LEN * BATCH * KCLS * 4) +       // logits
        pad((size_t)T_LEN * BATCH * 3 * 4);           // ang
    const size_t needA = base_bytes + pad((size_t)128 * BATCH * G4 * 2) * 2
                                    + pad((size_t)G4 * 1600 * 2) * 2;
    const int tierA = (ws_size >= needA + 4096) ? 1 : 0;
    const int W  = tierA ? 128 : 32;   // scan window (timesteps per xg chunk)
    const int NW = T_LEN / W;

    char* ws = (char*)d_ws;
    size_t off = 0;
    auto alloc = [&](size_t bytes) -> void* {
        off = (off + 255) & ~(size_t)255;
        void* p = ws + off;
        off += bytes;
        return p;
    };
    u16* xT    = (u16*)alloc((size_t)T_LEN * BATCH * DIN * 2);
    u16* h1    = (u16*)alloc((size_t)T_LEN * BATCH * 1600 * 2);
    u16* h2    = (u16*)alloc((size_t)T_LEN * BATCH * 1600 * 2);
    u16* w0fB  = (u16*)alloc((size_t)G4 * DIN * 2);
    u16* w0bB  = (u16*)alloc((size_t)G4 * DIN * 2);
    u16* P0f   = (u16*)alloc((size_t)G4 * HID * 2);
    u16* P0b   = (u16*)alloc((size_t)G4 * HID * 2);
    u16* P1f   = (u16*)alloc((size_t)G4 * HID * 2);
    u16* P1b   = (u16*)alloc((size_t)G4 * HID * 2);
    u16* linwB = (u16*)alloc((size_t)KCLS * 1600 * 2);
    u16* hzero = (u16*)alloc((size_t)BATCH * 1600 * 2);
    float* c0f = (float*)alloc((size_t)BATCH * HID * 4);
    float* c0b = (float*)alloc((size_t)BATCH * HID * 4);
    float* c1f = (float*)alloc((size_t)BATCH * HID * 4);
    float* c1b = (float*)alloc((size_t)BATCH * HID * 4);
    float* logitsF = (float*)alloc((size_t)T_LEN * BATCH * KCLS * 4);
    float* angF    = (float*)alloc((size_t)T_LEN * BATCH * 3 * 4);
    u16* xgFc  = (u16*)alloc((size_t)W * BATCH * G4 * 2);
    u16* xgBc  = (u16*)alloc((size_t)W * BATCH * G4 * 2);
    u16* w1fB  = nullptr;
    u16* w1bB  = nullptr;
    if (tierA){
        w1fB = (u16*)alloc((size_t)G4 * 1600 * 2);
        w1bB = (u16*)alloc((size_t)G4 * 1600 * 2);
    }

    // ---- prep ----
    k_zero16<<<dim3(32), dim3(256), 0, stream>>>(hzero, BATCH * 1600);
    k_cvt<<<dim3(128), dim3(256), 0, stream>>>(wih0f, w0fB, G4 * DIN);
    k_cvt<<<dim3(128), dim3(256), 0, stream>>>(wih0b, w0bB, G4 * DIN);
    k_cvt<<<dim3(64), dim3(256), 0, stream>>>(linw, linwB, KCLS * 1600);
    if (tierA){
        k_cvt<<<dim3(1024), dim3(256), 0, stream>>>(wih1f, w1fB, G4 * 1600);
        k_cvt<<<dim3(1024), dim3(256), 0, stream>>>(wih1b, w1bB, G4 * 1600);
    }
    k_pack_whh<<<dim3(1024), dim3(256), 0, stream>>>(whh0f, P0f);
    k_pack_whh<<<dim3(1024), dim3(256), 0, stream>>>(whh0b, P0b);
    k_pack_whh<<<dim3(1024), dim3(256), 0, stream>>>(whh1f, P1f);
    k_pack_whh<<<dim3(1024), dim3(256), 0, stream>>>(whh1b, P1b);
    k_xT<<<dim3(512), dim3(256), 0, stream>>>(x, xT);

    const int Mc = W * BATCH;           // rows per window GEMM
    const dim3 ggrid(G4 / 128, Mc / 128);

    // ---- layer 0: windowed xg GEMM + scan ----
    for (int w = 0; w < NW; ++w){
        const int t0f = w * W;
        const int t0b = T_LEN - (w + 1) * W;
        mfma_gemm<<<ggrid, dim3(256), 0, stream>>>(
            xT + (size_t)t0f * BATCH * DIN, DIN, w0fB, DIN, b0f,
            xgFc, G4, Mc, G4, DIN, 1, 0);
        mfma_gemm<<<ggrid, dim3(256), 0, stream>>>(
            xT + (size_t)t0b * BATCH * DIN, DIN, w0bB, DIN, b0b,
            xgBc, G4, Mc, G4, DIN, 1, 0);
        for (int q = 0; q < W; ++q){
            const int s = w * W + q;
            const int tf = s, tb = T_LEN - 1 - s;
            const u16* xgf_t = xgFc + (size_t)q * BATCH * G4;
            const u16* xgb_t = xgBc + (size_t)(W - 1 - q) * BATCH * G4;
            const u16* hpf = s ? h1 + (size_t)(s - 1) * BATCH * 1600        : hzero;
            const u16* hpb = s ? h1 + (size_t)(tb + 1) * BATCH * 1600 + 800 : hzero + 800;
            u16* hof = h1 + (size_t)tf * BATCH * 1600;
            u16* hob = h1 + (size_t)tb * BATCH * 1600 + 800;
            lstm_step<<<dim3(100), dim3(256), 0, stream>>>(
                xgf_t, xgb_t, P0f, P0b, hpf, hpb, hof, hob, c0f, c0b, s == 0 ? 1 : 0);
        }
    }

    // ---- layer 1: windowed xg GEMM + scan ----
    for (int w = 0; w < NW; ++w){
        const int t0f = w * W;
        const int t0b = T_LEN - (w + 1) * W;
        if (tierA){
            mfma_gemm<<<ggrid, dim3(256), 0, stream>>>(
                h1 + (size_t)t0f * BATCH * 1600, 1600, w1fB, 1600, b1f,
                xgFc, G4, Mc, G4, 1600, 1, 0);
            mfma_gemm<<<ggrid, dim3(256), 0, stream>>>(
                h1 + (size_t)t0b * BATCH * 1600, 1600, w1bB, 1600, b1b,
                xgBc, G4, Mc, G4, 1600, 1, 0);
        } else {
            mfma_gemm<<<ggrid, dim3(256), 0, stream>>>(
                h1 + (size_t)t0f * BATCH * 1600, 1600, wih1f, 1600, b1f,
                xgFc, G4, Mc, G4, 1600, 1, 1);
            mfma_gemm<<<ggrid, dim3(256), 0, stream>>>(
                h1 + (size_t)t0b * BATCH * 1600, 1600, wih1b, 1600, b1b,
                xgBc, G4, Mc, G4, 1600, 1, 1);
        }
        for (int q = 0; q < W; ++q){
            const int s = w * W + q;
            const int tf = s, tb = T_LEN - 1 - s;
            const u16* xgf_t = xgFc + (size_t)q * BATCH * G4;
            const u16* xgb_t = xgBc + (size_t)(W - 1 - q) * BATCH * G4;
            const u16* hpf = s ? h2 + (size_t)(s - 1) * BATCH * 1600        : hzero;
            const u16* hpb = s ? h2 + (size_t)(tb + 1) * BATCH * 1600 + 800 : hzero + 800;
            u16* hof = h2 + (size_t)tf * BATCH * 1600;
            u16* hob = h2 + (size_t)tb * BATCH * 1600 + 800;
            lstm_step<<<dim3(100), dim3(256), 0, stream>>>(
                xgf_t, xgb_t, P1f, P1b, hpf, hpb, hof, hob, c1f, c1b, s == 0 ? 1 : 0);
        }
    }

    // ---- logits (N=20, fp32 out) ----
    mfma_gemm<<<dim3(1, T_LEN * BATCH / 128), dim3(256), 0, stream>>>(
        h2, 1600, linwB, 1600, linb, logitsF, KCLS, T_LEN * BATCH, KCLS, 1600, 0, 0);

    k_smax_ang<<<dim3(T_LEN), dim3(64), 0, stream>>>(logitsF, alpha, angF);
    k_coords<<<dim3(1), dim3(64), 0, stream>>>(angF, (float*)d_out);
}